// Round 14
// baseline (136.723 us; speedup 1.0000x reference)
//
#include <hip/hip_runtime.h>
#include <hip/hip_fp16.h>

// COO SpMM: out[b,d] = sum_{e: row[e]==d} vals[e] * x[b, col[e]] + bias[d]
// B=64 (one wave), NUM_SRC=NUM_DST=100000, NNZ=3.2M, all fp32.
//
// R14: fused kernel frozen at its structural floor (85us; R8/R11/R12 ruled
// out wave count / MLP depth / instr count; fp16 payload taken). Prep:
// TILE back to 8192 so the scatter phase runs 392 blocks (1.5/CU) instead
// of 196 (0.77/CU) - R13's 16k tile starved CUs during scatter.

#define BSHIFT 7
#define BSIZE 128
#define MAXB 1024
#define TILE 8192
#define EPT 8        // TILE = EPT * 1024 (scatter)
#define BINCAP 4992  // per-bin region capacity (mean 4096 + 14 sigma)
#define SCAP 4672    // per-bin LDS edge capacity (mean 4096 + 9 sigma)
#define OVFCAP (1 << 20)

// ---------- combined: scatter blocks [0, nsb) + transpose blocks [nsb, ...) ----------
// scatter: tile counting-sort into fixed-capacity 128-dst bins,
//          gpk[bin*BINCAP+pos] = { (col<<7)|(row&127), bits(val) }
// transpose: x (64, nsrc) -> xTh (nsrc, 64) fp16
__global__ __launch_bounds__(1024) void prep_kernel(
    const float* __restrict__ x, __half* __restrict__ xTh,
    const int* __restrict__ row, const int* __restrict__ col,
    const float* __restrict__ vals, int* __restrict__ cursor,
    int2* __restrict__ gpk, int2* __restrict__ ovfA, float* __restrict__ ovfB,
    int* __restrict__ ovfCnt, int nnz, int nbins, int nsrc, int nsb) {
  __shared__ int cnt[MAXB];
  __shared__ int tb[MAXB];
  __shared__ float tile[64][65];
  if (blockIdx.x < nsb) {
    // ---- scatter section ----
    const int t0 = blockIdx.x * TILE;
    for (int j = threadIdx.x; j < nbins; j += 1024) cnt[j] = 0;
    __syncthreads();
    int rank[EPT];
#pragma unroll
    for (int k = 0; k < EPT; ++k) {
      int e = t0 + k * 1024 + threadIdx.x;
      if (e < nnz) rank[k] = atomicAdd(&cnt[row[e] >> BSHIFT], 1);
    }
    __syncthreads();
    // one global int cursor atomic per (tile, nonempty bin)
    for (int j = threadIdx.x; j < nbins; j += 1024) {
      int n = cnt[j];
      tb[j] = n ? atomicAdd(&cursor[j], n) : 0;
    }
    __syncthreads();
#pragma unroll
    for (int k = 0; k < EPT; ++k) {
      int e = t0 + k * 1024 + threadIdx.x;
      if (e < nnz) {
        int r = row[e], c = col[e];
        float v = vals[e];
        int b = r >> BSHIFT;
        int pos = tb[b] + rank[k];
        if (pos < BINCAP) {
          gpk[(size_t)b * BINCAP + pos] =
              make_int2((c << BSHIFT) | (r & (BSIZE - 1)), __float_as_int(v));
        } else {  // extremely rare: bin overflow -> fixup list
          int oi = atomicAdd(ovfCnt, 1);
          if (oi < OVFCAP) {
            ovfA[oi] = make_int2(c, r);
            ovfB[oi] = v;
          }
        }
      }
    }
  } else {
    // ---- transpose section ----
    int s0 = (blockIdx.x - nsb) * 64;
    int tx = threadIdx.x & 63;
    int ty = threadIdx.x >> 6;  // 0..15
#pragma unroll
    for (int i = 0; i < 4; ++i) {
      int b = ty + i * 16;
      int s = s0 + tx;
      tile[tx][b] = (s < nsrc) ? x[(size_t)b * nsrc + s] : 0.f;
    }
    __syncthreads();
#pragma unroll
    for (int i = 0; i < 4; ++i) {
      int sl = ty + i * 16;
      int s = s0 + sl;
      if (s < nsrc) xTh[(size_t)s * 64 + tx] = __float2half(tile[sl][tx]);
    }
  }
}

// ---------- fused: LDS sort of own bin + register spmm + epilogue (frozen) ----------
__global__ __launch_bounds__(512) void fused_spmm_kernel(
    const int2* __restrict__ gpk, const int* __restrict__ cursor,
    const __half* __restrict__ xTh, const float* __restrict__ bias,
    float* __restrict__ out, int2* __restrict__ ovfA, float* __restrict__ ovfB,
    int* __restrict__ ovfCnt, int ndst) {
  __shared__ int2 sedge[SCAP];
  __shared__ int cnt[BSIZE];
  __shared__ int exc[BSIZE];
  __shared__ int rk[BSIZE];
  const int b = blockIdx.x;
  const int t = threadIdx.x;
  int cur = cursor[b];
  const int n = (cur < BINCAP) ? cur : BINCAP;
  const int2* bg = gpk + (size_t)b * BINCAP;
  const int d0 = b << BSHIFT;
  if (t < BSIZE) {
    cnt[t] = 0;
    rk[t] = 0;
  }
  __syncthreads();
  // pass 1: per-dst histogram (gpk re-read is L2-hit)
  for (int e = t; e < n; e += 512) atomicAdd(&cnt[bg[e].x & (BSIZE - 1)], 1);
  __syncthreads();
  if (t < BSIZE) exc[t] = cnt[t];
  __syncthreads();
#pragma unroll
  for (int o = 1; o < BSIZE; o <<= 1) {
    int v = (t >= o && t < BSIZE) ? exc[t - o] : 0;
    __syncthreads();
    if (t < BSIZE) exc[t] += v;
    __syncthreads();
  }
  if (t < BSIZE) exc[t] -= cnt[t];  // exclusive
  __syncthreads();
  // pass 2: scatter into LDS in exact per-dst order
  for (int e = t; e < n; e += 512) {
    int2 p = bg[e];
    int dl = p.x & (BSIZE - 1);
    int pos = exc[dl] + atomicAdd(&rk[dl], 1);
    if (pos < SCAP) {
      sedge[pos] = p;
    } else {
      int oi = atomicAdd(ovfCnt, 1);
      if (oi < OVFCAP) {
        ovfA[oi] = make_int2(p.x >> BSHIFT, d0 + dl);
        ovfB[oi] = __int_as_float(p.y);
      }
    }
  }
  __syncthreads();
  // spmm: one wave per dst, 16 dsts/wave, register accumulate, 8-deep MLP
  const int lane = t & 63;
  const int w = t >> 6;  // 0..7
  float accq[16];
#pragma unroll
  for (int q = 0; q < 16; ++q) {
    const int dl = w + (q << 3);
    const int s = exc[dl];
    int e2 = s + cnt[dl];
    if (e2 > SCAP) e2 = SCAP;
    float acc = 0.f;
    int j = s;
    for (; j + 8 <= e2; j += 8) {
      int2 p[8];
#pragma unroll
      for (int k = 0; k < 8; ++k) p[k] = sedge[j + k];  // LDS broadcast
      float xv[8];
#pragma unroll
      for (int k = 0; k < 8; ++k)
        xv[k] = __half2float(xTh[((size_t)(p[k].x >> BSHIFT) << 6) + lane]);
#pragma unroll
      for (int k = 0; k < 8; ++k) acc = fmaf(__int_as_float(p[k].y), xv[k], acc);
    }
    for (; j < e2; ++j) {
      int2 p = sedge[j];
      acc = fmaf(__int_as_float(p.y),
                 __half2float(xTh[((size_t)(p.x >> BSHIFT) << 6) + lane]), acc);
    }
    accq[q] = acc;
  }
  __syncthreads();  // all sedge reads done; reuse as transpose buffer
  float* tr = (float*)sedge;  // 128*65*4 = 33280B <= SCAP*8
#pragma unroll
  for (int q = 0; q < 16; ++q) {
    const int dl = w + (q << 3);
    tr[dl * 65 + lane] = accq[q];
  }
  __syncthreads();
  // epilogue: out[br, d0+dl] = tr[dl][br] + bias[d]
  for (int i = t; i < BSIZE * 64; i += 512) {
    int dl = i & (BSIZE - 1);  // consecutive lanes -> consecutive d
    int br = i >> BSHIFT;
    int d = d0 + dl;
    if (d < ndst) out[(size_t)br * ndst + d] = tr[dl * 65 + br] + bias[d];
  }
}

// ---------- overflow fixup (expected empty) ----------
__global__ __launch_bounds__(256) void ovf_fix_kernel(
    const int2* __restrict__ ovfA, const float* __restrict__ ovfB,
    const int* __restrict__ ovfCnt, const __half* __restrict__ xTh,
    float* __restrict__ out, int ndst) {
  int n = *ovfCnt;
  if (n > OVFCAP) n = OVFCAP;
  const int lane = threadIdx.x & 63;
  const int w = threadIdx.x >> 6;
  for (int i = w; i < n; i += 4) {
    int2 cd = ovfA[i];
    float v = ovfB[i];
    float xv = __half2float(xTh[((size_t)cd.x << 6) + lane]);
    unsafeAtomicAdd(&out[(size_t)lane * ndst + cd.y], v * xv);
  }
}

extern "C" void kernel_launch(void* const* d_in, const int* in_sizes, int n_in,
                              void* d_out, int out_size, void* d_ws, size_t ws_size,
                              hipStream_t stream) {
  const float* x = (const float*)d_in[0];
  const float* vals = (const float*)d_in[1];
  const float* bias = (const float*)d_in[2];
  const int* row = (const int*)d_in[3];
  const int* col = (const int*)d_in[4];
  float* out = (float*)d_out;

  const int nnz = in_sizes[1];
  const int ndst = in_sizes[2];
  const int B = out_size / ndst;  // == 64 for this problem
  const int nsrc = in_sizes[0] / B;
  const int nbins = (ndst + BSIZE - 1) >> BSHIFT;  // 782 <= MAXB

  // workspace layout (256B-aligned chunks)
  size_t off = 0;
  auto take = [&](size_t bytes) {
    void* p = (char*)d_ws + off;
    off += (bytes + 255) & ~(size_t)255;
    return p;
  };
  __half* xTh = (__half*)take((size_t)nsrc * 64 * 2);
  int2* gpk = (int2*)take((size_t)nbins * BINCAP * 8);
  int2* ovfA = (int2*)take((size_t)OVFCAP * 8);
  float* ovfB = (float*)take((size_t)OVFCAP * 4);
  int* meta = (int*)take((size_t)(nbins + 64) * 4);  // cursor | ovfCnt
  int* cursor = meta;
  int* ovfCnt = meta + nbins;
  (void)ws_size;

  // single memset covers cursor + ovfCnt
  hipMemsetAsync(meta, 0, (size_t)(nbins + 1) * 4, stream);

  // 1. combined scatter (blocks 0..nsb-1) + transpose (rest)
  {
    int nsb = (nnz + TILE - 1) / TILE;         // scatter blocks (392)
    int ntb = (nsrc + 63) / 64;                // transpose blocks (1563)
    prep_kernel<<<nsb + ntb, 1024, 0, stream>>>(x, xTh, row, col, vals, cursor,
                                                gpk, ovfA, ovfB, ovfCnt, nnz,
                                                nbins, nsrc, nsb);
  }
  // 2. fused LDS sort + register spmm + epilogue (writes out + bias)
  fused_spmm_kernel<<<nbins, 512, 0, stream>>>(gpk, cursor, xTh, bias, out,
                                               ovfA, ovfB, ovfCnt, ndst);
  // 3. overflow fixup (expected no-op)
  ovf_fix_kernel<<<1, 256, 0, stream>>>(ovfA, ovfB, ovfCnt, xTh, out, ndst);
}

// Round 15
// 129.283 us; speedup vs baseline: 1.0575x; 1.0575x over previous
//
#include <hip/hip_runtime.h>
#include <hip/hip_fp16.h>

// COO SpMM: out[b,d] = sum_{e: row[e]==d} vals[e] * x[b, col[e]] + bias[d]
// B=64 (one wave), NUM_SRC=NUM_DST=100000, NNZ=3.2M, all fp32.
//
// R15: exact revert to R13 (measured best, 129.7us). R14's TILE=8192
// regressed prep (+7us: 2x cursor atomics + shorter runs beat the
// occupancy gain). fused_spmm frozen at structural floor (85us, R8/R11/R12
// triangulation: per-CU outstanding-miss cap at compulsory traffic).

#define BSHIFT 7
#define BSIZE 128
#define MAXB 1024
#define TILE 16384
#define EPT 16       // TILE = EPT * 1024 (scatter)
#define BINCAP 4992  // per-bin region capacity (mean 4096 + 14 sigma)
#define SCAP 4672    // per-bin LDS edge capacity (mean 4096 + 9 sigma)
#define OVFCAP (1 << 20)

// ---------- combined: scatter blocks [0, nsb) + transpose blocks [nsb, ...) ----------
// scatter: tile counting-sort into fixed-capacity 128-dst bins,
//          gpk[bin*BINCAP+pos] = { (col<<7)|(row&127), bits(val) }
// transpose: x (64, nsrc) -> xTh (nsrc, 64) fp16
__global__ __launch_bounds__(1024) void prep_kernel(
    const float* __restrict__ x, __half* __restrict__ xTh,
    const int* __restrict__ row, const int* __restrict__ col,
    const float* __restrict__ vals, int* __restrict__ cursor,
    int2* __restrict__ gpk, int2* __restrict__ ovfA, float* __restrict__ ovfB,
    int* __restrict__ ovfCnt, int nnz, int nbins, int nsrc, int nsb) {
  __shared__ int cnt[MAXB];
  __shared__ int tb[MAXB];
  __shared__ float tile[64][65];
  if (blockIdx.x < nsb) {
    // ---- scatter section ----
    const int t0 = blockIdx.x * TILE;
    for (int j = threadIdx.x; j < nbins; j += 1024) cnt[j] = 0;
    __syncthreads();
    int rank[EPT];
#pragma unroll
    for (int k = 0; k < EPT; ++k) {
      int e = t0 + k * 1024 + threadIdx.x;
      if (e < nnz) rank[k] = atomicAdd(&cnt[row[e] >> BSHIFT], 1);
    }
    __syncthreads();
    // one global int cursor atomic per (tile, nonempty bin)
    for (int j = threadIdx.x; j < nbins; j += 1024) {
      int n = cnt[j];
      tb[j] = n ? atomicAdd(&cursor[j], n) : 0;
    }
    __syncthreads();
#pragma unroll
    for (int k = 0; k < EPT; ++k) {
      int e = t0 + k * 1024 + threadIdx.x;
      if (e < nnz) {
        int r = row[e], c = col[e];
        float v = vals[e];
        int b = r >> BSHIFT;
        int pos = tb[b] + rank[k];
        if (pos < BINCAP) {
          gpk[(size_t)b * BINCAP + pos] =
              make_int2((c << BSHIFT) | (r & (BSIZE - 1)), __float_as_int(v));
        } else {  // extremely rare: bin overflow -> fixup list
          int oi = atomicAdd(ovfCnt, 1);
          if (oi < OVFCAP) {
            ovfA[oi] = make_int2(c, r);
            ovfB[oi] = v;
          }
        }
      }
    }
  } else {
    // ---- transpose section ----
    int s0 = (blockIdx.x - nsb) * 64;
    int tx = threadIdx.x & 63;
    int ty = threadIdx.x >> 6;  // 0..15
#pragma unroll
    for (int i = 0; i < 4; ++i) {
      int b = ty + i * 16;
      int s = s0 + tx;
      tile[tx][b] = (s < nsrc) ? x[(size_t)b * nsrc + s] : 0.f;
    }
    __syncthreads();
#pragma unroll
    for (int i = 0; i < 4; ++i) {
      int sl = ty + i * 16;
      int s = s0 + sl;
      if (s < nsrc) xTh[(size_t)s * 64 + tx] = __float2half(tile[sl][tx]);
    }
  }
}

// ---------- fused: LDS sort of own bin + register spmm + epilogue (frozen) ----------
__global__ __launch_bounds__(512) void fused_spmm_kernel(
    const int2* __restrict__ gpk, const int* __restrict__ cursor,
    const __half* __restrict__ xTh, const float* __restrict__ bias,
    float* __restrict__ out, int2* __restrict__ ovfA, float* __restrict__ ovfB,
    int* __restrict__ ovfCnt, int ndst) {
  __shared__ int2 sedge[SCAP];
  __shared__ int cnt[BSIZE];
  __shared__ int exc[BSIZE];
  __shared__ int rk[BSIZE];
  const int b = blockIdx.x;
  const int t = threadIdx.x;
  int cur = cursor[b];
  const int n = (cur < BINCAP) ? cur : BINCAP;
  const int2* bg = gpk + (size_t)b * BINCAP;
  const int d0 = b << BSHIFT;
  if (t < BSIZE) {
    cnt[t] = 0;
    rk[t] = 0;
  }
  __syncthreads();
  // pass 1: per-dst histogram (gpk re-read is L2-hit)
  for (int e = t; e < n; e += 512) atomicAdd(&cnt[bg[e].x & (BSIZE - 1)], 1);
  __syncthreads();
  if (t < BSIZE) exc[t] = cnt[t];
  __syncthreads();
#pragma unroll
  for (int o = 1; o < BSIZE; o <<= 1) {
    int v = (t >= o && t < BSIZE) ? exc[t - o] : 0;
    __syncthreads();
    if (t < BSIZE) exc[t] += v;
    __syncthreads();
  }
  if (t < BSIZE) exc[t] -= cnt[t];  // exclusive
  __syncthreads();
  // pass 2: scatter into LDS in exact per-dst order
  for (int e = t; e < n; e += 512) {
    int2 p = bg[e];
    int dl = p.x & (BSIZE - 1);
    int pos = exc[dl] + atomicAdd(&rk[dl], 1);
    if (pos < SCAP) {
      sedge[pos] = p;
    } else {
      int oi = atomicAdd(ovfCnt, 1);
      if (oi < OVFCAP) {
        ovfA[oi] = make_int2(p.x >> BSHIFT, d0 + dl);
        ovfB[oi] = __int_as_float(p.y);
      }
    }
  }
  __syncthreads();
  // spmm: one wave per dst, 16 dsts/wave, register accumulate, 8-deep MLP
  const int lane = t & 63;
  const int w = t >> 6;  // 0..7
  float accq[16];
#pragma unroll
  for (int q = 0; q < 16; ++q) {
    const int dl = w + (q << 3);
    const int s = exc[dl];
    int e2 = s + cnt[dl];
    if (e2 > SCAP) e2 = SCAP;
    float acc = 0.f;
    int j = s;
    for (; j + 8 <= e2; j += 8) {
      int2 p[8];
#pragma unroll
      for (int k = 0; k < 8; ++k) p[k] = sedge[j + k];  // LDS broadcast
      float xv[8];
#pragma unroll
      for (int k = 0; k < 8; ++k)
        xv[k] = __half2float(xTh[((size_t)(p[k].x >> BSHIFT) << 6) + lane]);
#pragma unroll
      for (int k = 0; k < 8; ++k) acc = fmaf(__int_as_float(p[k].y), xv[k], acc);
    }
    for (; j < e2; ++j) {
      int2 p = sedge[j];
      acc = fmaf(__int_as_float(p.y),
                 __half2float(xTh[((size_t)(p.x >> BSHIFT) << 6) + lane]), acc);
    }
    accq[q] = acc;
  }
  __syncthreads();  // all sedge reads done; reuse as transpose buffer
  float* tr = (float*)sedge;  // 128*65*4 = 33280B <= SCAP*8
#pragma unroll
  for (int q = 0; q < 16; ++q) {
    const int dl = w + (q << 3);
    tr[dl * 65 + lane] = accq[q];
  }
  __syncthreads();
  // epilogue: out[br, d0+dl] = tr[dl][br] + bias[d]
  for (int i = t; i < BSIZE * 64; i += 512) {
    int dl = i & (BSIZE - 1);  // consecutive lanes -> consecutive d
    int br = i >> BSHIFT;
    int d = d0 + dl;
    if (d < ndst) out[(size_t)br * ndst + d] = tr[dl * 65 + br] + bias[d];
  }
}

// ---------- overflow fixup (expected empty) ----------
__global__ __launch_bounds__(256) void ovf_fix_kernel(
    const int2* __restrict__ ovfA, const float* __restrict__ ovfB,
    const int* __restrict__ ovfCnt, const __half* __restrict__ xTh,
    float* __restrict__ out, int ndst) {
  int n = *ovfCnt;
  if (n > OVFCAP) n = OVFCAP;
  const int lane = threadIdx.x & 63;
  const int w = threadIdx.x >> 6;
  for (int i = w; i < n; i += 4) {
    int2 cd = ovfA[i];
    float v = ovfB[i];
    float xv = __half2float(xTh[((size_t)cd.x << 6) + lane]);
    unsafeAtomicAdd(&out[(size_t)lane * ndst + cd.y], v * xv);
  }
}

extern "C" void kernel_launch(void* const* d_in, const int* in_sizes, int n_in,
                              void* d_out, int out_size, void* d_ws, size_t ws_size,
                              hipStream_t stream) {
  const float* x = (const float*)d_in[0];
  const float* vals = (const float*)d_in[1];
  const float* bias = (const float*)d_in[2];
  const int* row = (const int*)d_in[3];
  const int* col = (const int*)d_in[4];
  float* out = (float*)d_out;

  const int nnz = in_sizes[1];
  const int ndst = in_sizes[2];
  const int B = out_size / ndst;  // == 64 for this problem
  const int nsrc = in_sizes[0] / B;
  const int nbins = (ndst + BSIZE - 1) >> BSHIFT;  // 782 <= MAXB

  // workspace layout (256B-aligned chunks)
  size_t off = 0;
  auto take = [&](size_t bytes) {
    void* p = (char*)d_ws + off;
    off += (bytes + 255) & ~(size_t)255;
    return p;
  };
  __half* xTh = (__half*)take((size_t)nsrc * 64 * 2);
  int2* gpk = (int2*)take((size_t)nbins * BINCAP * 8);
  int2* ovfA = (int2*)take((size_t)OVFCAP * 8);
  float* ovfB = (float*)take((size_t)OVFCAP * 4);
  int* meta = (int*)take((size_t)(nbins + 64) * 4);  // cursor | ovfCnt
  int* cursor = meta;
  int* ovfCnt = meta + nbins;
  (void)ws_size;

  // single memset covers cursor + ovfCnt
  hipMemsetAsync(meta, 0, (size_t)(nbins + 1) * 4, stream);

  // 1. combined scatter (blocks 0..nsb-1) + transpose (rest)
  {
    int nsb = (nnz + TILE - 1) / TILE;         // scatter blocks (196)
    int ntb = (nsrc + 63) / 64;                // transpose blocks (1563)
    prep_kernel<<<nsb + ntb, 1024, 0, stream>>>(x, xTh, row, col, vals, cursor,
                                                gpk, ovfA, ovfB, ovfCnt, nnz,
                                                nbins, nsrc, nsb);
  }
  // 2. fused LDS sort + register spmm + epilogue (writes out + bias)
  fused_spmm_kernel<<<nbins, 512, 0, stream>>>(gpk, cursor, xTh, bias, out,
                                               ovfA, ovfB, ovfCnt, ndst);
  // 3. overflow fixup (expected no-op)
  ovf_fix_kernel<<<1, 256, 0, stream>>>(ovfA, ovfB, ovfCnt, xTh, out, ndst);
}